// Round 6
// baseline (110.519 us; speedup 1.0000x reference)
//
#include <hip/hip_runtime.h>

// AxonalConnections: out[n,b,:,:] = sum over 4 incoming edges (src -> n) of
//   spikes[src,b] * masks[src] * weights[e]
// Topology is compile-time: src(e) = e>>2, dst(e) = (src + (e&3) + 1) & 7.
//
// Lessons so far:
//  r1: re-loadable values + loop -> compiler sinks loads, re-reads weights 4x.
//  r3: f32x2 single-pass, zero redundancy: 92 us (best). VALUBusy 3%, occ 38%.
//  r4: two-pass over weights -> 2nd pass misses L3 (streams > 256MB), +120MB HBM.
//  r5: batch-across-lanes: occupancy 78% but 4x redundant weight lanes -> 104 us.
//      => limiter is per-wave-instruction memory throughput, NOT TLP, NOT HBM.
//
// This version = r3's exact structure (single pass, zero redundancy, batch in
// registers) but f32x4 (16 B/lane): halves vector-mem instructions vs r3.
// Fully straight-line (src/k/b all unrolled), every load used exactly once,
// so nothing is sinkable. acc[8][4] = 128 VGPR; launch_bounds(256,2) allows
// up to 256 VGPR -> no spill, ~3 waves/SIMD (r3's occupancy region).
// Ideal HBM traffic: 288 MB read + 128 MB write = 416 MB (~66 us @ 6.3 TB/s).

#define HW (1024 * 1024)   // H*W pixels
#define NN 8               // nodes
#define NB 4               // batch

typedef float f32x4 __attribute__((ext_vector_type(4)));

__global__ __launch_bounds__(256, 2) void axon_kernel(
    const float* __restrict__ spikes,   // [N, B, HW]
    const float* __restrict__ masks,    // [N, HW]
    const float* __restrict__ weights,  // [E, HW]
    float* __restrict__ out)            // [N, B, HW]
{
    const int t = blockIdx.x * blockDim.x + threadIdx.x;  // 0 .. HW/4 - 1
    const int p = t * 4;                                  // float offset in a plane

    f32x4 acc[NN][NB];
#pragma unroll
    for (int n = 0; n < NN; ++n)
#pragma unroll
        for (int b = 0; b < NB; ++b) acc[n][b] = (f32x4)(0.0f);

#pragma unroll
    for (int src = 0; src < NN; ++src) {
        const f32x4 m = *reinterpret_cast<const f32x4*>(masks + src * HW + p);

        f32x4 s[NB];
#pragma unroll
        for (int b = 0; b < NB; ++b) {
            s[b] = *reinterpret_cast<const f32x4*>(spikes + (src * NB + b) * HW + p);
            s[b] *= m;   // pre-scale by source mask; feeds all 4 outgoing edges
        }

#pragma unroll
        for (int k = 0; k < 4; ++k) {
            const int e   = src * 4 + k;
            const int dst = (src + k + 1) & 7;
            const f32x4 w = *reinterpret_cast<const f32x4*>(weights + e * HW + p);
#pragma unroll
            for (int b = 0; b < NB; ++b)
#pragma unroll
                for (int c = 0; c < 4; ++c)
                    acc[dst][b][c] = fmaf(s[b][c], w[c], acc[dst][b][c]);
        }
    }

#pragma unroll
    for (int n = 0; n < NN; ++n)
#pragma unroll
        for (int b = 0; b < NB; ++b)
            __builtin_nontemporal_store(
                acc[n][b], reinterpret_cast<f32x4*>(out + (n * NB + b) * HW + p));
}

extern "C" void kernel_launch(void* const* d_in, const int* in_sizes, int n_in,
                              void* d_out, int out_size, void* d_ws, size_t ws_size,
                              hipStream_t stream) {
    const float* spikes  = (const float*)d_in[0];  // [8,4,1024,1024]
    const float* masks   = (const float*)d_in[1];  // [8,1024,1024]
    const float* weights = (const float*)d_in[2];  // [32,1024,1024]
    float* out = (float*)d_out;                    // [8,4,1024,1024]

    const int threads = 256;
    const int blocks  = (HW / 4) / threads;        // 1024 blocks, 1 thread / 4 pixels
    axon_kernel<<<blocks, threads, 0, stream>>>(spikes, masks, weights, out);
}

// Round 7
// 85.871 us; speedup vs baseline: 1.2870x; 1.2870x over previous
//
#include <hip/hip_runtime.h>

// AxonalConnections: out[n,b,:,:] = sum over 4 incoming edges (src -> n) of
//   spikes[src,b] * masks[src] * weights[e]
// Topology is compile-time: src(e) = e>>2, dst(e) = (src + (e&3) + 1) & 7.
//
// Lessons:
//  r1: compiler sinks re-loadable loads -> 4x weight re-reads.
//  r3: f32x2 single-pass zero-redundancy: 92 us (best so far).
//  r4: any 2nd pass over weights misses L3 (streams > 256MB) -> +120MB HBM.
//  r5: TLP (occ 78%) does NOT help; redundant lanes hurt.
//  r6: halving vmem insts (f32x4) does NOT help.
//  => limiter is loads-in-flight per wave: compiler always minimizes live
//     VGPRs (52..88) and spaces loads into small latency-exposed bursts.
//
// This version: r3's exact structure, but ALL 72 loads are issued as one
// burst and pinned above the compute with sched_barrier(0) so the scheduler
// cannot sink them. ~36 KiB of outstanding loads per wave hides HBM latency
// even at 2-3 waves/SIMD. launch_bounds(256,2) gives the RA 256 VGPRs.
// Ideal HBM traffic: 288 MiB read + 128 MiB write (~69 us @ 6.3 TB/s).

#define HW (1024 * 1024)   // H*W pixels
#define NN 8               // nodes
#define NB 4               // batch

typedef float f32x2 __attribute__((ext_vector_type(2)));

__global__ __launch_bounds__(256, 2) void axon_kernel(
    const float* __restrict__ spikes,   // [N, B, HW]
    const float* __restrict__ masks,    // [N, HW]
    const float* __restrict__ weights,  // [E, HW]
    float* __restrict__ out)            // [N, B, HW]
{
    const int t = blockIdx.x * blockDim.x + threadIdx.x;  // 0 .. HW/2 - 1
    const int p = t * 2;                                  // float offset in a plane

    // ---- one big load burst: every input byte this thread will ever touch ----
    f32x2 m[NN], s[NN][NB], w[32];
#pragma unroll
    for (int n = 0; n < NN; ++n)
        m[n] = *reinterpret_cast<const f32x2*>(masks + n * HW + p);
#pragma unroll
    for (int n = 0; n < NN; ++n)
#pragma unroll
        for (int b = 0; b < NB; ++b)
            s[n][b] = *reinterpret_cast<const f32x2*>(spikes + (n * NB + b) * HW + p);
#pragma unroll
    for (int e = 0; e < 32; ++e)
        w[e] = *reinterpret_cast<const f32x2*>(weights + e * HW + p);

    // fence: scheduler may not sink any of the loads above into the compute
    __builtin_amdgcn_sched_barrier(0);

    f32x2 acc[NN][NB];
#pragma unroll
    for (int n = 0; n < NN; ++n)
#pragma unroll
        for (int b = 0; b < NB; ++b) acc[n][b] = (f32x2)(0.0f);

#pragma unroll
    for (int src = 0; src < NN; ++src) {
        // pre-scale spikes by source mask (feeds all 4 outgoing edges)
#pragma unroll
        for (int b = 0; b < NB; ++b) s[src][b] *= m[src];

#pragma unroll
        for (int k = 0; k < 4; ++k) {
            const int e   = src * 4 + k;
            const int dst = (src + k + 1) & 7;
#pragma unroll
            for (int b = 0; b < NB; ++b) {
                acc[dst][b].x = fmaf(s[src][b].x, w[e].x, acc[dst][b].x);
                acc[dst][b].y = fmaf(s[src][b].y, w[e].y, acc[dst][b].y);
            }
        }
    }

#pragma unroll
    for (int n = 0; n < NN; ++n)
#pragma unroll
        for (int b = 0; b < NB; ++b)
            __builtin_nontemporal_store(
                acc[n][b], reinterpret_cast<f32x2*>(out + (n * NB + b) * HW + p));
}

extern "C" void kernel_launch(void* const* d_in, const int* in_sizes, int n_in,
                              void* d_out, int out_size, void* d_ws, size_t ws_size,
                              hipStream_t stream) {
    const float* spikes  = (const float*)d_in[0];  // [8,4,1024,1024]
    const float* masks   = (const float*)d_in[1];  // [8,1024,1024]
    const float* weights = (const float*)d_in[2];  // [32,1024,1024]
    float* out = (float*)d_out;                    // [8,4,1024,1024]

    const int threads = 256;
    const int blocks  = (HW / 2) / threads;        // 2048 blocks, 1 thread / 2 pixels
    axon_kernel<<<blocks, threads, 0, stream>>>(spikes, masks, weights, out);
}